// Round 20
// baseline (226.691 us; speedup 1.0000x reference)
//
#include <hip/hip_runtime.h>

#define B_ 512
#define T_ 512
#define V_ 96
#define H_ 128
#define XST 132   // xwl row stride (floats): banks shift 4*id -> gather spread
#define K2F 2.8853900817779268f   // 2*log2(e): exp(2s) == exp2(K2F*s)

typedef _Float16 half8 __attribute__((ext_vector_type(8)));
typedef float    f32x4 __attribute__((ext_vector_type(4)));

// Pass 1a: recover the one-hot index per (b,t). x is exactly {0.0, 1.0}.
__global__ __launch_bounds__(256) void onehot_idx_kernel(
    const float4* __restrict__ x4, int n4, int* __restrict__ idx)
{
    int stride = gridDim.x * blockDim.x;
    for (int e4 = blockIdx.x * blockDim.x + threadIdx.x; e4 < n4; e4 += stride) {
        float4 v = x4[e4];
        int base = e4 * 4;
        if (v.x > 0.5f) idx[(base + 0) / V_] = (base + 0) % V_;
        if (v.y > 0.5f) idx[(base + 1) / V_] = (base + 1) % V_;
        if (v.z > 0.5f) idx[(base + 2) / V_] = (base + 2) % V_;
        if (v.w > 0.5f) idx[(base + 3) / V_] = (base + 3) % V_;
    }
}

// Pass 1b (R16-VERIFIED): xwg[v][u'] with u' = (u&15)*8 + (u>>4); a lane's
// per-row xw pair for n-tiles {2w, 2w+1} is one aligned float2.
__global__ __launch_bounds__(256) void build_xwg_kernel(
    const float* __restrict__ W_ih, const float* __restrict__ b_ih,
    const float* __restrict__ b_hh, float* __restrict__ xwg)
{
    int e = blockIdx.x * 256 + threadIdx.x;
    if (e < V_ * H_) {
        int v = e >> 7, up = e & 127;
        int u = (up & 7) * 16 + (up >> 3);
        xwg[e] = (W_ih[u * V_ + v] + b_ih[u] + b_hh[u]) * K2F;
    }
}

// Pass 1c (R16-VERIFIED): recurrence B-frags, K2F pre-scaled f16.
__global__ __launch_bounds__(256) void build_wB_kernel(
    const float* __restrict__ W_hh, _Float16* __restrict__ wB)
{
    int e = blockIdx.x * 256 + threadIdx.x;     // 4ks*8nt*64lane*8reg = 16384
    if (e < 16384) {
        int reg = e & 7, lane = (e >> 3) & 63, nt = (e >> 9) & 7, ks = e >> 12;
        int unit = ks * 32 + (lane >> 4) * 8 + reg;
        int n    = nt * 16 + (lane & 15);
        wB[e] = (_Float16)(K2F * W_hh[n * H_ + unit]);
    }
}

// Pass 1d (R16-VERIFIED): fc B-frags (unscaled W_fc, f16), 6 n-tiles.
__global__ __launch_bounds__(256) void build_wBfc_kernel(
    const float* __restrict__ W_fc, _Float16* __restrict__ wBfc)
{
    int e = blockIdx.x * 256 + threadIdx.x;     // 4*6*64*8 = 12288
    if (e < 12288) {
        int reg = e & 7, lane = (e >> 3) & 63;
        int nt = (e >> 9) % 6, ks = e / 3072;
        int unit = ks * 32 + (lane >> 4) * 8 + reg;
        int n    = nt * 16 + (lane & 15);
        wBfc[e] = (_Float16)W_fc[n * H_ + unit];
    }
}

// One recurrence step with COMPILE-TIME buffer index (2-step unroll):
// A-reads issue first (immediates, no cur-math); xw for t+1 gathered in the
// MFMA shadow; xw(t) pre-folded as MFMA C-init (p-chains) -> tail is
// exp2(acc) directly. One __syncthreads per step (lgkm-only drain).
#define RNN_STEP(CUR, TNXT)                                                   \
  do {                                                                        \
    half8 aF[4];                                                              \
    _Pragma("unroll")                                                         \
    for (int ks = 0; ks < 4; ++ks)                                            \
      __builtin_memcpy(&aF[ks], &hs[CUR][lo][ks * 32 + g * 8], 16);           \
    unsigned idw2;                                                            \
    __builtin_memcpy(&idw2, &idxT[(TNXT) * 16 + 4 * g], 4);                   \
    float2 xwn[4];                                                            \
    _Pragma("unroll")                                                         \
    for (int j = 0; j < 4; ++j) {                                             \
      int id = (idwN >> (8 * j)) & 255;                                       \
      __builtin_memcpy(&xwn[j], &xwl[id * XST + lo * 8 + 2 * w], 8);          \
    }                                                                         \
    f32x4 p0 = {xwc[0].x, xwc[1].x, xwc[2].x, xwc[3].x};                      \
    f32x4 p1 = {xwc[0].y, xwc[1].y, xwc[2].y, xwc[3].y};                      \
    f32x4 q0 = {0.f, 0.f, 0.f, 0.f}, q1 = {0.f, 0.f, 0.f, 0.f};               \
    _Pragma("unroll")                                                         \
    for (int ks = 0; ks < 2; ++ks) {                                          \
      union { uint4 u; half8 h; } u0, u1, u2, u3;                             \
      u0.u = wb[ks][0];     u1.u = wb[ks][1];                                 \
      u2.u = wb[ks + 2][0]; u3.u = wb[ks + 2][1];                             \
      p0 = __builtin_amdgcn_mfma_f32_16x16x32_f16(aF[ks],     u0.h, p0, 0,0,0);\
      p1 = __builtin_amdgcn_mfma_f32_16x16x32_f16(aF[ks],     u1.h, p1, 0,0,0);\
      q0 = __builtin_amdgcn_mfma_f32_16x16x32_f16(aF[ks + 2], u2.h, q0, 0,0,0);\
      q1 = __builtin_amdgcn_mfma_f32_16x16x32_f16(aF[ks + 2], u3.h, q1, 0,0,0);\
    }                                                                         \
    f32x4 acc0 = p0 + q0, acc1 = p1 + q1;                                     \
    _Pragma("unroll")                                                         \
    for (int j = 0; j < 4; ++j) {                                             \
      float E0 = __builtin_amdgcn_exp2f(acc0[j]);                             \
      float E1 = __builtin_amdgcn_exp2f(acc1[j]);                             \
      float h0 = 1.0f - 2.0f * __builtin_amdgcn_rcpf(E0 + 1.0f);              \
      float h1 = 1.0f - 2.0f * __builtin_amdgcn_rcpf(E1 + 1.0f);              \
      hs[(CUR) ^ 1][4 * g + j][(2 * w + 0) * 16 + lo] = (_Float16)h0;         \
      hs[(CUR) ^ 1][4 * g + j][(2 * w + 1) * 16 + lo] = (_Float16)h1;         \
    }                                                                         \
    _Pragma("unroll")                                                         \
    for (int j = 0; j < 4; ++j) xwc[j] = xwn[j];                              \
    idwN = idw2;                                                              \
    __syncthreads();                                                          \
  } while (0)

__global__ __launch_bounds__(256, 1) void rnn_mfma4_kernel(
    const uint4* __restrict__ wBg, const uint4* __restrict__ wBfcg,
    const float* __restrict__ xwg, const int* __restrict__ idx,
    const float* __restrict__ b_fc, float* __restrict__ out)
{
    const int bb  = blockIdx.x;        // rows 16*bb .. 16*bb+15
    const int tid = threadIdx.x;
    const int w   = tid >> 6;          // wave 0..3 -> n-tiles {2w, 2w+1}
    const int l   = tid & 63;
    const int lo  = l & 15, g = l >> 4;

    __shared__ float         xwl[V_ * XST];       // 50.7 KiB LDS gather table
    __shared__ _Float16      hs[2][16][136];      // dbl-buffered h, +8 pad
    __shared__ unsigned char idxT[(T_ + 2) * 16]; // [t][row] char ids

    for (int e = tid; e < V_ * H_; e += 256) {
        int v = e >> 7, up = e & 127;
        xwl[v * XST + up] = xwg[e];
    }
    for (int e = tid; e < 16 * T_; e += 256) {
        int row = e >> 9, t = e & 511;
        idxT[t * 16 + row] = (unsigned char)idx[(bb * 16 + row) * T_ + t];
    }
    if (tid < 32) idxT[T_ * 16 + tid] = 0;        // pad for t+2/t+3 lookahead
    for (int e = tid; e < 16 * 136; e += 256)
        hs[0][e / 136][e % 136] = (_Float16)0.f;

    // this wave's B-frags: 8 x uint4 = 32 regs, loaded ONCE
    uint4 wb[4][2];
    #pragma unroll
    for (int ks = 0; ks < 4; ++ks)
        #pragma unroll
        for (int q = 0; q < 2; ++q)
            wb[ks][q] = wBg[(ks * 8 + 2 * w + q) * 64 + l];

    __syncthreads();

    // prologue: xw(t=0) in regs, idw for t=1
    float2 xwc[4];
    unsigned idwN;
    {
        unsigned idw0;
        __builtin_memcpy(&idw0, &idxT[0 * 16 + 4 * g], 4);
        #pragma unroll
        for (int j = 0; j < 4; ++j) {
            int id = (idw0 >> (8 * j)) & 255;
            __builtin_memcpy(&xwc[j], &xwl[id * XST + lo * 8 + 2 * w], 8);
        }
        __builtin_memcpy(&idwN, &idxT[1 * 16 + 4 * g], 4);
    }

    #pragma clang loop unroll(disable)
    for (int t = 0; t < T_; t += 2) {
        RNN_STEP(0, t + 2);       // reads hs[0], writes hs[1]
        RNN_STEP(1, t + 3);       // reads hs[1], writes hs[0]
    }

    // fc epilogue (final h is in hs[0] after an even number of steps)
    half8 aE[4];
    #pragma unroll
    for (int ks = 0; ks < 4; ++ks)
        __builtin_memcpy(&aE[ks], &hs[0][lo][ks * 32 + g * 8], 16);
    #pragma unroll
    for (int q = 0; q < 2; ++q) {
        const int NT = 2 * w + q;
        if (NT < 6) {
            float bf = b_fc[NT * 16 + lo];
            f32x4 acc = {bf, bf, bf, bf};
            #pragma unroll
            for (int ks = 0; ks < 4; ++ks) {
                union { uint4 u; half8 h; } ub;
                ub.u = wBfcg[(ks * 6 + NT) * 64 + l];
                acc = __builtin_amdgcn_mfma_f32_16x16x32_f16(aE[ks], ub.h, acc, 0, 0, 0);
            }
            #pragma unroll
            for (int j = 0; j < 4; ++j)
                out[(bb * 16 + 4 * g + j) * V_ + NT * 16 + lo] = acc[j];
        }
    }
}

extern "C" void kernel_launch(void* const* d_in, const int* in_sizes, int n_in,
                              void* d_out, int out_size, void* d_ws, size_t ws_size,
                              hipStream_t stream)
{
    const float* x    = (const float*)d_in[0];
    const float* W_ih = (const float*)d_in[1];
    const float* b_ih = (const float*)d_in[2];
    const float* W_hh = (const float*)d_in[3];
    const float* b_hh = (const float*)d_in[4];
    const float* W_fc = (const float*)d_in[5];
    const float* b_fc = (const float*)d_in[6];
    float* out = (float*)d_out;

    char* ws = (char*)d_ws;
    int*      idx  = (int*)ws;                               // 1 MiB
    float*    xwg  = (float*)(ws + (size_t)B_ * T_ * 4);     // 48 KiB
    _Float16* wB   = (_Float16*)((char*)xwg + V_ * H_ * 4);  // 32 KiB
    _Float16* wBfc = (_Float16*)((char*)wB + 16384 * 2);     // 24 KiB

    const int n4 = (B_ * T_ * V_) / 4;
    hipLaunchKernelGGL(onehot_idx_kernel, dim3(2048), dim3(256), 0, stream,
                       (const float4*)x, n4, idx);
    hipLaunchKernelGGL(build_xwg_kernel, dim3((V_ * H_ + 255) / 256), dim3(256),
                       0, stream, W_ih, b_ih, b_hh, xwg);
    hipLaunchKernelGGL(build_wB_kernel, dim3(64), dim3(256), 0, stream, W_hh, wB);
    hipLaunchKernelGGL(build_wBfc_kernel, dim3(48), dim3(256), 0, stream, W_fc, wBfc);
    hipLaunchKernelGGL(rnn_mfma4_kernel, dim3(B_ / 16), dim3(256), 0, stream,
                       (const uint4*)wB, (const uint4*)wBfc, xwg, idx, b_fc, out);
}

// Round 21
// 198.039 us; speedup vs baseline: 1.1447x; 1.1447x over previous
//
#include <hip/hip_runtime.h>

#define B_ 512
#define T_ 512
#define V_ 96
#define H_ 128
#define XST 132   // xwl row stride (floats)
#define K2F 2.8853900817779268f   // 2*log2(e): exp(2s) == exp2(K2F*s)

typedef _Float16 half8 __attribute__((ext_vector_type(8)));
typedef float    f32x4 __attribute__((ext_vector_type(4)));

// Pass 1a: recover the one-hot index per (b,t). x is exactly {0.0, 1.0}.
__global__ __launch_bounds__(256) void onehot_idx_kernel(
    const float4* __restrict__ x4, int n4, int* __restrict__ idx)
{
    int stride = gridDim.x * blockDim.x;
    for (int e4 = blockIdx.x * blockDim.x + threadIdx.x; e4 < n4; e4 += stride) {
        float4 v = x4[e4];
        int base = e4 * 4;
        if (v.x > 0.5f) idx[(base + 0) / V_] = (base + 0) % V_;
        if (v.y > 0.5f) idx[(base + 1) / V_] = (base + 1) % V_;
        if (v.z > 0.5f) idx[(base + 2) / V_] = (base + 2) % V_;
        if (v.w > 0.5f) idx[(base + 3) / V_] = (base + 3) % V_;
    }
}

// Pass 1b: PLAIN xwg[v][u] = (W_ih[u][v] + b_ih[u] + b_hh[u]) * K2F.
// With the swapped MFMA, a lane's C-init is xwg[id][4-consecutive units]:
// a single float4, no permutation needed.
__global__ __launch_bounds__(256) void build_xwg_kernel(
    const float* __restrict__ W_ih, const float* __restrict__ b_ih,
    const float* __restrict__ b_hh, float* __restrict__ xwg)
{
    int e = blockIdx.x * 256 + threadIdx.x;
    if (e < V_ * H_) {
        int v = e >> 7, u = e & 127;
        xwg[e] = (W_ih[u * V_ + v] + b_ih[u] + b_hh[u]) * K2F;
    }
}

// Pass 1c (R16-VERIFIED builder, reused as A-frags): frag (ks,mt): lane
// holds A[m = mt*16+(lane&15)][k = ks*32+(lane>>4)*8+reg] = K2F*W_hh[m][k].
// (A and B fragment layouts are symmetric: same builder, nt renamed mt.)
__global__ __launch_bounds__(256) void build_wB_kernel(
    const float* __restrict__ W_hh, _Float16* __restrict__ wB)
{
    int e = blockIdx.x * 256 + threadIdx.x;     // 4ks*8mt*64lane*8reg = 16384
    if (e < 16384) {
        int reg = e & 7, lane = (e >> 3) & 63, mt = (e >> 9) & 7, ks = e >> 12;
        int kin = ks * 32 + (lane >> 4) * 8 + reg;
        int m   = mt * 16 + (lane & 15);
        wB[e] = (_Float16)(K2F * W_hh[m * H_ + kin]);
    }
}

// Pass 1d (R16-VERIFIED builder): fc A-frags (unscaled W_fc), 6 m-tiles.
__global__ __launch_bounds__(256) void build_wBfc_kernel(
    const float* __restrict__ W_fc, _Float16* __restrict__ wBfc)
{
    int e = blockIdx.x * 256 + threadIdx.x;     // 4*6*64*8 = 12288
    if (e < 12288) {
        int reg = e & 7, lane = (e >> 3) & 63;
        int mt = (e >> 9) % 6, ks = e / 3072;
        int kin = ks * 32 + (lane >> 4) * 8 + reg;
        int m   = mt * 16 + (lane & 15);
        wBfc[e] = (_Float16)W_fc[m * H_ + kin];
    }
}

// Pass 2: 4 waves / 16 rows / block, grid=32; SWAPPED MFMA OPERANDS.
// D[m=unit][n=row] = mfma(A=W_hh frag, B=h frag): lane owns 4 CONSECUTIVE
// units of ONE row -> h write is 2x ds_write_b64 (was 8x b16), xw C-init is
// 2x float4 LDS reads (was 4x b64 + byte packing), B=h read unchanged.
// DS-pipe per CU-step drops ~640 -> ~360 cy (R20 showed we are DS-bound).
// Zero vmem in the loop (R19 lesson); verified builders reused unchanged.
__global__ __launch_bounds__(256, 1) void rnn_mfma4_kernel(
    const uint4* __restrict__ wBg, const uint4* __restrict__ wBfcg,
    const float* __restrict__ xwg, const int* __restrict__ idx,
    const float* __restrict__ b_fc, float* __restrict__ out)
{
    const int bb  = blockIdx.x;        // rows 16*bb .. 16*bb+15
    const int tid = threadIdx.x;
    const int w   = tid >> 6;          // wave 0..3 -> unit m-tiles {2w, 2w+1}
    const int l   = tid & 63;
    const int lo  = l & 15, g = l >> 4;

    __shared__ float         xwl[V_ * XST];   // 50.7 KiB gather table [v][u]
    __shared__ _Float16      hs[2][16][136];  // dbl-buffered h[row][unit]
    __shared__ unsigned char idxT[T_ * 16];   // [t][row] char ids

    for (int e = tid; e < V_ * H_; e += 256) {
        int v = e >> 7, u = e & 127;
        xwl[v * XST + u] = xwg[e];
    }
    for (int e = tid; e < 16 * T_; e += 256) {
        int row = e >> 9, t = e & 511;
        idxT[t * 16 + row] = (unsigned char)idx[(bb * 16 + row) * T_ + t];
    }
    for (int e = tid; e < 16 * 136; e += 256)
        hs[0][e / 136][e % 136] = (_Float16)0.f;

    // this wave's weight A-frags: 8 x uint4 = 32 regs, loaded ONCE
    uint4 wa[4][2];
    #pragma unroll
    for (int ks = 0; ks < 4; ++ks)
        #pragma unroll
        for (int q = 0; q < 2; ++q)
            wa[ks][q] = wBg[(ks * 8 + 2 * w + q) * 64 + l];

    __syncthreads();

    int cur = 0;
    #pragma clang loop unroll(disable)
    for (int t = 0; t < T_; ++t) {
        // this lane's row id (LDS byte, 16 distinct addrs -> broadcast-ish)
        const int id = idxT[t * 16 + lo];

        // C-init gather: units {32w+4g..+3} and {32w+16+4g..+3} of row id
        f32x4 xw0, xw1;
        __builtin_memcpy(&xw0, &xwl[id * XST + 32 * w + 4 * g], 16);
        __builtin_memcpy(&xw1, &xwl[id * XST + 32 * w + 16 + 4 * g], 16);

        // B-frags: h_{t-1} of own row, k-contiguous (4x b128, unchanged)
        half8 bF[4];
        #pragma unroll
        for (int ks = 0; ks < 4; ++ks)
            __builtin_memcpy(&bF[ks], &hs[cur][lo][ks * 32 + g * 8], 16);

        // 8 MFMAs, 2+2 split chains; xw folded as C-init of the p-chains
        f32x4 p0 = xw0, p1 = xw1;
        f32x4 q0 = {0.f, 0.f, 0.f, 0.f}, q1 = {0.f, 0.f, 0.f, 0.f};
        #pragma unroll
        for (int ks = 0; ks < 2; ++ks) {
            union { uint4 u; half8 h; } u0, u1, u2, u3;
            u0.u = wa[ks][0];     u1.u = wa[ks][1];
            u2.u = wa[ks + 2][0]; u3.u = wa[ks + 2][1];
            p0 = __builtin_amdgcn_mfma_f32_16x16x32_f16(u0.h, bF[ks],     p0, 0, 0, 0);
            p1 = __builtin_amdgcn_mfma_f32_16x16x32_f16(u1.h, bF[ks],     p1, 0, 0, 0);
            q0 = __builtin_amdgcn_mfma_f32_16x16x32_f16(u2.h, bF[ks + 2], q0, 0, 0, 0);
            q1 = __builtin_amdgcn_mfma_f32_16x16x32_f16(u3.h, bF[ks + 2], q1, 0, 0, 0);
        }
        f32x4 acc0 = p0 + q0, acc1 = p1 + q1;

        // tail: tanh(s) = 1 - 2/(exp2(acc)+1); pack 4 halves -> one b64 write
        _Float16 o0[4], o1[4];
        #pragma unroll
        for (int j = 0; j < 4; ++j) {
            float E0 = __builtin_amdgcn_exp2f(acc0[j]);
            float E1 = __builtin_amdgcn_exp2f(acc1[j]);
            o0[j] = (_Float16)(1.0f - 2.0f * __builtin_amdgcn_rcpf(E0 + 1.0f));
            o1[j] = (_Float16)(1.0f - 2.0f * __builtin_amdgcn_rcpf(E1 + 1.0f));
        }
        __builtin_memcpy(&hs[cur ^ 1][lo][32 * w + 4 * g], o0, 8);
        __builtin_memcpy(&hs[cur ^ 1][lo][32 * w + 16 + 4 * g], o1, 8);
        cur ^= 1;
        __syncthreads();                       // lgkm-only drain
    }

    // fc epilogue: D[m=vocab][n=row]; wave w does vocab m-tiles {2w,2w+1}<6
    half8 bE[4];
    #pragma unroll
    for (int ks = 0; ks < 4; ++ks)
        __builtin_memcpy(&bE[ks], &hs[cur][lo][ks * 32 + g * 8], 16);
    #pragma unroll
    for (int q = 0; q < 2; ++q) {
        const int MT = 2 * w + q;
        if (MT < 6) {
            f32x4 acc;
            __builtin_memcpy(&acc, &b_fc[MT * 16 + 4 * g], 16);  // C-init bias
            #pragma unroll
            for (int ks = 0; ks < 4; ++ks) {
                union { uint4 u; half8 h; } ua;
                ua.u = wBfcg[(ks * 6 + MT) * 64 + l];
                acc = __builtin_amdgcn_mfma_f32_16x16x32_f16(ua.h, bE[ks], acc, 0, 0, 0);
            }
            __builtin_memcpy(&out[(bb * 16 + lo) * V_ + MT * 16 + 4 * g], &acc, 16);
        }
    }
}

extern "C" void kernel_launch(void* const* d_in, const int* in_sizes, int n_in,
                              void* d_out, int out_size, void* d_ws, size_t ws_size,
                              hipStream_t stream)
{
    const float* x    = (const float*)d_in[0];
    const float* W_ih = (const float*)d_in[1];
    const float* b_ih = (const float*)d_in[2];
    const float* W_hh = (const float*)d_in[3];
    const float* b_hh = (const float*)d_in[4];
    const float* W_fc = (const float*)d_in[5];
    const float* b_fc = (const float*)d_in[6];
    float* out = (float*)d_out;

    char* ws = (char*)d_ws;
    int*      idx  = (int*)ws;                               // 1 MiB
    float*    xwg  = (float*)(ws + (size_t)B_ * T_ * 4);     // 48 KiB
    _Float16* wB   = (_Float16*)((char*)xwg + V_ * H_ * 4);  // 32 KiB
    _Float16* wBfc = (_Float16*)((char*)wB + 16384 * 2);     // 24 KiB

    const int n4 = (B_ * T_ * V_) / 4;
    hipLaunchKernelGGL(onehot_idx_kernel, dim3(2048), dim3(256), 0, stream,
                       (const float4*)x, n4, idx);
    hipLaunchKernelGGL(build_xwg_kernel, dim3((V_ * H_ + 255) / 256), dim3(256),
                       0, stream, W_ih, b_ih, b_hh, xwg);
    hipLaunchKernelGGL(build_wB_kernel, dim3(64), dim3(256), 0, stream, W_hh, wB);
    hipLaunchKernelGGL(build_wBfc_kernel, dim3(48), dim3(256), 0, stream, W_fc, wBfc);
    hipLaunchKernelGGL(rnn_mfma4_kernel, dim3(B_ / 16), dim3(256), 0, stream,
                       (const uint4*)wB, (const uint4*)wBfc, xwg, idx, b_fc, out);
}